// Round 1
// baseline (2145.101 us; speedup 1.0000x reference)
//
#include <hip/hip_runtime.h>
#include <hip/hip_bf16.h>

// LocallyHierarchicalNet: 10 locally-connected layers (stride=kernel=2) + mean + beta matmul.
// Strategy round 0: correctness-first MFMA (16x16x32 bf16, verified fragment layouts),
// direct global gathers (no LDS), split-K atomics for tail layers, runtime dtype probe.

#define B_   128
#define H_   256
#define OUT_ 10

typedef __attribute__((ext_vector_type(4))) float floatx4;
typedef __attribute__((ext_vector_type(8))) short shortx8;

__device__ __forceinline__ float bf2f(unsigned short u){
    union { unsigned int u; float f; } c; c.u = ((unsigned int)u) << 16; return c.f;
}
__device__ __forceinline__ unsigned short f2bf(float f){
    union { float f; unsigned int u; } c; c.f = f;
    unsigned int x = c.u;
    x += 0x7FFFu + ((x >> 16) & 1u);   // round-to-nearest-even
    return (unsigned short)(x >> 16);
}

// ---------------------------------------------------------------------------
// dtype probe: low 16 bits of the first 256 dwords of x.
// bf16 data -> each 16b half is a bf16 of N(0,1): exponent field concentrated.
// fp32 data -> low half is mantissa bits: exponent-field ~uniform (only ~21% in range).
__global__ void probe_kernel(const unsigned int* __restrict__ x, int* __restrict__ flag){
    __shared__ int cnt[256];
    int tid = threadIdx.x;
    unsigned short lo = (unsigned short)(x[tid] & 0xFFFFu);
    int e = (lo >> 7) & 0xFF;
    cnt[tid] = (e >= 90 && e <= 143) ? 1 : 0;
    __syncthreads();
    for (int s = 128; s > 0; s >>= 1){
        if (tid < s) cnt[tid] += cnt[tid + s];
        __syncthreads();
    }
    if (tid == 0) *flag = (cnt[0] > 160) ? 1 : 0;   // 1 => inputs are bf16
}

// ---------------------------------------------------------------------------
// Layer 0: out S0[b,o,d] = sum_{c<3,t<2} x[b,c,2d+t] * w0[o,c,d,t]   (raw, bf16)
template<bool BF>
__device__ __forceinline__ void l0_impl(const void* __restrict__ xv, const void* __restrict__ wv,
                                        unsigned short* __restrict__ out){
    const float* xF = (const float*)xv;
    const unsigned short* xB = (const unsigned short*)xv;
    const float* wF = (const float*)wv;
    const unsigned short* wB = (const unsigned short*)wv;
    int bo = blockIdx.x;
    int b = bo >> 8, o = bo & 255;
    for (int d = threadIdx.x; d < 512; d += 256){
        float s = 0.f;
        #pragma unroll
        for (int c = 0; c < 3; ++c){
            int xi = (b*3 + c)*1024 + 2*d;
            int wi = ((o*3 + c)*512 + d)*2;
            float x0, x1, w0, w1;
            if (BF){
                unsigned int ux = *(const unsigned int*)(xB + xi);
                unsigned int uw = *(const unsigned int*)(wB + wi);
                x0 = bf2f((unsigned short)(ux & 0xFFFFu)); x1 = bf2f((unsigned short)(ux >> 16));
                w0 = bf2f((unsigned short)(uw & 0xFFFFu)); w1 = bf2f((unsigned short)(uw >> 16));
            } else {
                x0 = xF[xi]; x1 = xF[xi+1];
                w0 = wF[wi]; w1 = wF[wi+1];
            }
            s += x0*w0 + x1*w1;
        }
        out[(b*256 + o)*512 + d] = f2bf(s);
    }
}
__global__ __launch_bounds__(256) void l0_kernel(const int* __restrict__ flag,
                                                 const void* x, const void* w, unsigned short* out){
    if (*flag) l0_impl<true>(x, w, out);
    else       l0_impl<false>(x, w, out);
}

// ---------------------------------------------------------------------------
// Main layer (layers 1..9): per position d, GEMM M=128(b) x N=256(o) x K=512(c,t).
// Input act = raw sums of previous layer; a = relu(act) * in_scale applied on load.
// Output: raw sums. ATOMIC=true -> fp32 atomicAdd (split-K); else bf16 store.
// MFMA 16x16x32 bf16, verified layouts:
//   A: m=lane&15, k=(lane>>4)*8+j ; B: n=lane&15, same k ; D: col=lane&15, row=(lane>>4)*4+reg
template<bool WBF, bool ABF, bool ATOMIC>
__device__ __forceinline__ void layer_impl(const void* __restrict__ act, const void* __restrict__ w,
                                           void* __restrict__ out, int dl, float in_scale, int ksplit){
    const int Dl = dl << 1;                // input spatial length
    int id = blockIdx.x;
    int d  = id % dl;
    int t2 = id / dl;
    int ob = t2 & 3;                       // o-block of 64
    int ks = t2 >> 2;                      // split-K id
    const int KSEG = 512 / ksplit;
    const int K0s  = ks * KSEG;

    int lane = threadIdx.x & 63;
    int wv2  = threadIdx.x >> 6;           // wave id 0..3 -> b rows [wv*32, wv*32+32)
    int mr   = lane & 15;
    int kg   = lane >> 4;

    const float* aF = (const float*)act;
    const unsigned short* aB = (const unsigned short*)act;
    const float* wF = (const float*)w;
    const unsigned short* wB = (const unsigned short*)w;

    floatx4 acc[2][4];
    #pragma unroll
    for (int mi = 0; mi < 2; ++mi)
        #pragma unroll
        for (int ni = 0; ni < 4; ++ni)
            acc[mi][ni] = (floatx4){0.f, 0.f, 0.f, 0.f};

    for (int k0 = K0s; k0 < K0s + KSEG; k0 += 32){
        int c0 = (k0 + kg*8) >> 1;         // 4 consecutive c per lane, t=0,1 pairs
        shortx8 afrag[2];
        #pragma unroll
        for (int mi = 0; mi < 2; ++mi){
            int b = (wv2 << 5) + (mi << 4) + mr;
            int base = (b*256 + c0)*Dl + 2*d;
            #pragma unroll
            for (int cc = 0; cc < 4; ++cc){
                float v0, v1;
                if (ABF){
                    unsigned int u = *(const unsigned int*)(aB + base);
                    v0 = bf2f((unsigned short)(u & 0xFFFFu));
                    v1 = bf2f((unsigned short)(u >> 16));
                } else {
                    v0 = aF[base]; v1 = aF[base + 1];
                }
                v0 = fmaxf(v0, 0.f) * in_scale;
                v1 = fmaxf(v1, 0.f) * in_scale;
                afrag[mi][2*cc]   = (short)f2bf(v0);
                afrag[mi][2*cc+1] = (short)f2bf(v1);
                base += Dl;
            }
        }
        shortx8 bfrag[4];
        #pragma unroll
        for (int ni = 0; ni < 4; ++ni){
            int o = (ob << 6) + (ni << 4) + mr;
            int base = ((o*256 + c0)*dl + d) << 1;
            #pragma unroll
            for (int cc = 0; cc < 4; ++cc){
                if (WBF){
                    unsigned int u = *(const unsigned int*)(wB + base);
                    bfrag[ni][2*cc]   = (short)(u & 0xFFFFu);
                    bfrag[ni][2*cc+1] = (short)(u >> 16);
                } else {
                    bfrag[ni][2*cc]   = (short)f2bf(wF[base]);
                    bfrag[ni][2*cc+1] = (short)f2bf(wF[base + 1]);
                }
                base += (dl << 1);
            }
        }
        #pragma unroll
        for (int mi = 0; mi < 2; ++mi)
            #pragma unroll
            for (int ni = 0; ni < 4; ++ni)
                acc[mi][ni] = __builtin_amdgcn_mfma_f32_16x16x32_bf16(afrag[mi], bfrag[ni], acc[mi][ni], 0, 0, 0);
    }

    #pragma unroll
    for (int mi = 0; mi < 2; ++mi){
        #pragma unroll
        for (int ni = 0; ni < 4; ++ni){
            int o = (ob << 6) + (ni << 4) + mr;
            #pragma unroll
            for (int r = 0; r < 4; ++r){
                int b = (wv2 << 5) + (mi << 4) + (kg << 2) + r;
                int idx = (b*256 + o)*dl + d;
                float v = acc[mi][ni][r];
                if (ATOMIC) unsafeAtomicAdd((float*)out + idx, v);
                else ((unsigned short*)out)[idx] = f2bf(v);
            }
        }
    }
}

template<bool ABF, bool ATOMIC>
__global__ __launch_bounds__(256) void layer_kernel(const int* __restrict__ flag,
                                                    const void* act, const void* w, void* out,
                                                    int dl, float in_scale, int ksplit){
    if (*flag) layer_impl<true,  ABF, ATOMIC>(act, w, out, dl, in_scale, ksplit);
    else       layer_impl<false, ABF, ATOMIC>(act, w, out, dl, in_scale, ksplit);
}

// ---------------------------------------------------------------------------
// Epilogue: y[b,h] = relu(S9[b,h])/16 ; out[b,o] = sum_h y*beta[h,o] / 256
template<bool BF>
__device__ __forceinline__ void epi_impl(const float* __restrict__ S9, const void* __restrict__ beta,
                                         void* __restrict__ out){
    int b = blockIdx.x;
    int lane = threadIdx.x;   // 64 threads = 1 wave
    float accv[OUT_];
    #pragma unroll
    for (int o = 0; o < OUT_; ++o) accv[o] = 0.f;
    for (int h = lane; h < 256; h += 64){
        float y = fmaxf(S9[b*256 + h], 0.f) * 0.0625f;
        #pragma unroll
        for (int o = 0; o < OUT_; ++o){
            float be = BF ? bf2f(((const unsigned short*)beta)[h*OUT_ + o])
                          : ((const float*)beta)[h*OUT_ + o];
            accv[o] += y * be;
        }
    }
    #pragma unroll
    for (int off = 32; off > 0; off >>= 1){
        #pragma unroll
        for (int o = 0; o < OUT_; ++o)
            accv[o] += __shfl_down(accv[o], off, 64);
    }
    if (lane == 0){
        #pragma unroll
        for (int o = 0; o < OUT_; ++o){
            float v = accv[o] * (1.f/256.f);
            if (BF) ((unsigned short*)out)[b*OUT_ + o] = f2bf(v);
            else    ((float*)out)[b*OUT_ + o] = v;
        }
    }
}
__global__ void epi_kernel(const int* __restrict__ flag, const float* S9, const void* beta, void* out){
    if (*flag) epi_impl<true>(S9, beta, out);
    else       epi_impl<false>(S9, beta, out);
}

// ---------------------------------------------------------------------------
extern "C" void kernel_launch(void* const* d_in, const int* in_sizes, int n_in,
                              void* d_out, int out_size, void* d_ws, size_t ws_size,
                              hipStream_t stream) {
    (void)in_sizes; (void)n_in; (void)out_size; (void)ws_size;
    char* wsb = (char*)d_ws;
    int* flag = (int*)wsb;
    unsigned short* bufA = (unsigned short*)(wsb + 512);                       // 33.55 MB (L0/L2 out)
    unsigned short* bufB = (unsigned short*)(wsb + 512 + 33554432);            // 16.78 MB (L1/L3 out)
    float* Ftail = (float*)(wsb + 512 + 33554432 + 16777216);                  // 8.26 MB fp32 tail
    const int TAIL_ELEMS = 128*256*63;
    float* F4 = Ftail;
    float* F5 = F4 + 128*256*32;
    float* F6 = F5 + 128*256*16;
    float* F7 = F6 + 128*256*8;
    float* F8 = F7 + 128*256*4;
    float* F9 = F8 + 128*256*2;

    const float INV_SQRT3 = 0.57735026918962576f;
    const float INV16 = 0.0625f;

    probe_kernel<<<1, 256, 0, stream>>>((const unsigned int*)d_in[0], flag);
    hipMemsetAsync(Ftail, 0, TAIL_ELEMS*sizeof(float), stream);   // split-K accumulators

    // layer 0 (K=6, vector)
    l0_kernel<<<B_*H_, 256, 0, stream>>>(flag, d_in[0], d_in[1], bufA);
    // layers 1..9: grid = dl * 4 o-blocks * ksplit
    layer_kernel<true,  false><<<256*4,    256, 0, stream>>>(flag, bufA, d_in[2],  bufB, 256, INV_SQRT3, 1);
    layer_kernel<true,  false><<<128*4,    256, 0, stream>>>(flag, bufB, d_in[3],  bufA, 128, INV16, 1);
    layer_kernel<true,  false><<<64*4,     256, 0, stream>>>(flag, bufA, d_in[4],  bufB, 64,  INV16, 1);
    layer_kernel<true,  true ><<<32*4*2,   256, 0, stream>>>(flag, bufB, d_in[5],  F4,  32,  INV16, 2);
    layer_kernel<false, true ><<<16*4*4,   256, 0, stream>>>(flag, F4,  d_in[6],  F5,  16,  INV16, 4);
    layer_kernel<false, true ><<<8*4*8,    256, 0, stream>>>(flag, F5,  d_in[7],  F6,  8,   INV16, 8);
    layer_kernel<false, true ><<<4*4*16,   256, 0, stream>>>(flag, F6,  d_in[8],  F7,  4,   INV16, 16);
    layer_kernel<false, true ><<<2*4*16,   256, 0, stream>>>(flag, F7,  d_in[9],  F8,  2,   INV16, 16);
    layer_kernel<false, true ><<<1*4*16,   256, 0, stream>>>(flag, F8,  d_in[10], F9,  1,   INV16, 16);
    // epilogue
    epi_kernel<<<B_, 64, 0, stream>>>(flag, F9, d_in[11], d_out);
}

// Round 2
// 642.372 us; speedup vs baseline: 3.3393x; 3.3393x over previous
//
#include <hip/hip_runtime.h>
#include <hip/hip_bf16.h>
#include <stdint.h>

// R2: coalesced restructure.
// - Acts stored as A[p][b][c] bf16, post-relu, pre-scaled (self-contained layer input).
// - Main layer kernel: block = (d-group of 4, o-group of 64, k-slice); wave <-> d.
//   Weights staged global->LDS along contiguous (d,t) runs, transposed to MFMA-B layout.
//   A staged global->LDS as coalesced dwordx4 rows. 16x16x32 bf16 MFMA, k = t*16+c.
// - l1 writes bf16 A directly; l2..l9 atomic-accumulate fp32 S[p][b][o] (split-K),
//   finalize kernels do relu*(1/16)+bf16 relayout (identity index map).
// - Tail (dl<=2): round-0-style gather (weights ~1MB, L2-resident).
// WS (50.3 MB): [flag 512B][region1 33.55MB: A1 then S2..S9 (memset after l1)]
//               [region2 16.78MB: A2 then A3..A9 overlay after l2]

typedef __attribute__((ext_vector_type(4))) float floatx4;
typedef __attribute__((ext_vector_type(8))) short shortx8;

__device__ __forceinline__ float bf2f(unsigned short u){
    union { unsigned int u; float f; } c; c.u = ((unsigned int)u) << 16; return c.f;
}
__device__ __forceinline__ unsigned short f2bf(float f){
    union { float f; unsigned int u; } c; c.f = f;
    unsigned int x = c.u;
    x += 0x7FFFu + ((x >> 16) & 1u);
    return (unsigned short)(x >> 16);
}

// ---------------------------------------------------------------------------
// dtype probe (unchanged from R1, verified working)
__global__ void probe_kernel(const unsigned int* __restrict__ x, int* __restrict__ flag){
    __shared__ int cnt[256];
    int tid = threadIdx.x;
    unsigned short lo = (unsigned short)(x[tid] & 0xFFFFu);
    int e = (lo >> 7) & 0xFF;
    cnt[tid] = (e >= 90 && e <= 143) ? 1 : 0;
    __syncthreads();
    for (int s = 128; s > 0; s >>= 1){
        if (tid < s) cnt[tid] += cnt[tid + s];
        __syncthreads();
    }
    if (tid == 0) *flag = (cnt[0] > 160) ? 1 : 0;
}

// ---------------------------------------------------------------------------
// Layer 0: A1[p=d][b][o] = relu(sum_{c,t} x[b,c,2d+t]*w0[o,c,d,t]) * (1/sqrt(3))
__global__ __launch_bounds__(256) void l0_kernel(const int* __restrict__ flag,
        const void* __restrict__ xv, const void* __restrict__ wv,
        unsigned short* __restrict__ A1){
    __shared__ float Xs[128*6];
    const int d = blockIdx.x;
    const int tid = threadIdx.x;
    const bool BF = (*flag != 0);
    for (int i = tid; i < 384; i += 256){
        int b = i / 3, c = i - b*3;
        if (BF){
            unsigned int u = *(const unsigned int*)((const unsigned short*)xv + (b*3+c)*1024 + 2*d);
            Xs[b*6 + c*2]     = bf2f((unsigned short)(u & 0xFFFFu));
            Xs[b*6 + c*2 + 1] = bf2f((unsigned short)(u >> 16));
        } else {
            const float* xf = (const float*)xv + (b*3+c)*1024 + 2*d;
            Xs[b*6 + c*2] = xf[0]; Xs[b*6 + c*2 + 1] = xf[1];
        }
    }
    __syncthreads();
    const int o = tid;
    float wr[6];
    #pragma unroll
    for (int c = 0; c < 3; ++c){
        if (BF){
            unsigned int u = *(const unsigned int*)((const unsigned short*)wv + ((o*3+c)*512 + d)*2);
            wr[c*2]   = bf2f((unsigned short)(u & 0xFFFFu));
            wr[c*2+1] = bf2f((unsigned short)(u >> 16));
        } else {
            const float* wf = (const float*)wv + ((o*3+c)*512 + d)*2;
            wr[c*2] = wf[0]; wr[c*2+1] = wf[1];
        }
    }
    const float s3 = 0.57735026918962576f;
    for (int b = 0; b < 128; ++b){
        float s = 0.f;
        #pragma unroll
        for (int j = 0; j < 6; ++j) s += Xs[b*6 + j] * wr[j];
        A1[d*32768 + b*256 + o] = f2bf(fmaxf(s, 0.f) * s3);
    }
}

// ---------------------------------------------------------------------------
// Main layer kernel. grid = (dl/4) * 4 * ks. Block: d-group d0..d0+3 (wave<->d),
// o-group of 64, k-slice of (16/ks) c-chunks. M=128 full batch.
// k-order within a K=32 MFMA step: k = t*16 + c_local  (g = lane>>4: t=g>>1, chalf=g&1).
template<bool WBF, bool ATOMIC>
__device__ __forceinline__ void layer_main_impl(const unsigned short* __restrict__ Ain,
        const void* __restrict__ wv, void* __restrict__ out, int dl, int ks){
    __shared__ unsigned short At[8*128*16];   // [p_local 8][b 128][c 16]  32 KB
    __shared__ unsigned short Wt[4*64*40];    // [d 4][o 64][t*16+c, pad->40] 20 KB
    const int tid  = threadIdx.x;
    const int lane = tid & 63, wv_ = tid >> 6;
    const int g = lane >> 4, mr = lane & 15;
    const int nd = dl >> 2;
    int bi = blockIdx.x;
    const int dg = bi % nd; bi /= nd;
    const int ng = bi & 3;
    const int ksid = bi >> 2;
    const int TS = 16 / ks;
    const int d0 = dg << 2;
    const int o0 = ng << 6;
    const int dme = d0 + wv_;
    const float* wF = (const float*)wv;
    const unsigned short* wB = (const unsigned short*)wv;

    floatx4 acc[8][4];
    #pragma unroll
    for (int m = 0; m < 8; ++m)
        #pragma unroll
        for (int nb = 0; nb < 4; ++nb)
            acc[m][nb] = (floatx4){0.f,0.f,0.f,0.f};

    for (int s = 0; s < TS; ++s){
        const int c0 = (ksid*TS + s) << 4;
        // ---- stage A: 8 p-rows x 128 b x 16 c, coalesced dwordx4
        {
            const int b = tid >> 1, h = tid & 1;
            #pragma unroll
            for (int i = 0; i < 8; ++i){
                uint4 v = *(const uint4*)(Ain + (2*d0 + i)*32768 + b*256 + c0 + h*8);
                *(uint4*)(At + (i*128 + b)*16 + h*8) = v;
            }
        }
        // ---- stage W: 1024 (o,c)-runs of 8 elems (d0..d0+3 x t0,t1), transpose on LDS write
        #pragma unroll
        for (int rr = 0; rr < 4; ++rr){
            int run = (rr << 8) + tid;
            int oo = run >> 4, cl = run & 15;
            int src = ((((o0 + oo) << 8) + (c0 + cl))*dl + d0)*2;
            unsigned short wtmp[8];
            if (WBF){
                uint4 u = *(const uint4*)(wB + src);
                const unsigned short* pu = (const unsigned short*)&u;
                #pragma unroll
                for (int j = 0; j < 8; ++j) wtmp[j] = pu[j];
            } else {
                float4 a = *(const float4*)(wF + src);
                float4 b4 = *(const float4*)(wF + src + 4);
                wtmp[0]=f2bf(a.x); wtmp[1]=f2bf(a.y); wtmp[2]=f2bf(a.z); wtmp[3]=f2bf(a.w);
                wtmp[4]=f2bf(b4.x); wtmp[5]=f2bf(b4.y); wtmp[6]=f2bf(b4.z); wtmp[7]=f2bf(b4.w);
            }
            #pragma unroll
            for (int j = 0; j < 8; ++j){
                int dd = j >> 1, t = j & 1;
                Wt[(dd*64 + oo)*40 + t*16 + cl] = wtmp[j];
            }
        }
        __syncthreads();
        // ---- compute: wave's d = d0+wv_, 4 n-tiles x 8 m-tiles
        shortx8 bfr[4];
        #pragma unroll
        for (int nb = 0; nb < 4; ++nb)
            bfr[nb] = *(const shortx8*)(Wt + (wv_*64 + nb*16 + mr)*40 + g*8);
        #pragma unroll
        for (int m = 0; m < 8; ++m){
            shortx8 af = *(const shortx8*)(At + ((wv_*2 + (g>>1))*128 + m*16 + mr)*16 + (g&1)*8);
            #pragma unroll
            for (int nb = 0; nb < 4; ++nb)
                acc[m][nb] = __builtin_amdgcn_mfma_f32_16x16x32_bf16(af, bfr[nb], acc[m][nb], 0,0,0);
        }
        __syncthreads();
    }
    // ---- epilogue: D row=g*4+r -> b, col=mr -> o
    #pragma unroll
    for (int m = 0; m < 8; ++m)
        #pragma unroll
        for (int nb = 0; nb < 4; ++nb)
            #pragma unroll
            for (int r = 0; r < 4; ++r){
                int b = m*16 + g*4 + r;
                int o = o0 + nb*16 + mr;
                if (ATOMIC)
                    unsafeAtomicAdd((float*)out + (dme*128 + b)*256 + o, acc[m][nb][r]);
                else
                    ((unsigned short*)out)[dme*32768 + b*256 + o] =
                        f2bf(fmaxf(acc[m][nb][r], 0.f) * 0.0625f);
            }
}

template<bool ATOMIC>
__global__ __launch_bounds__(256,2) void layer_main_k(const int* __restrict__ flag,
        const unsigned short* __restrict__ Ain, const void* __restrict__ wv,
        void* __restrict__ out, int dl, int ks){
    if (*flag) layer_main_impl<true,  ATOMIC>(Ain, wv, out, dl, ks);
    else       layer_main_impl<false, ATOMIC>(Ain, wv, out, dl, ks);
}

// ---------------------------------------------------------------------------
// Tail layers (dl<=2): direct gather (weights ~1MB, L2-resident), atomic fp32 out.
// k-order c-minor: k = c*2 + t.
template<bool WBF>
__device__ __forceinline__ void tail_impl(const unsigned short* __restrict__ Ain,
        const void* __restrict__ wv, float* __restrict__ outS, int dl, int ksplit){
    int id = blockIdx.x;
    int d = id % dl; int t2 = id / dl;
    int ob = t2 & 3; int ksid = t2 >> 2;
    const int KSEG = 512 / ksplit;
    const int k0s = ksid * KSEG;
    const int lane = threadIdx.x & 63, wv2 = threadIdx.x >> 6;
    const int mr = lane & 15, kg = lane >> 4;
    const float* wF = (const float*)wv;
    const unsigned short* wB = (const unsigned short*)wv;
    floatx4 acc[2][4];
    #pragma unroll
    for (int mi = 0; mi < 2; ++mi)
        #pragma unroll
        for (int ni = 0; ni < 4; ++ni) acc[mi][ni] = (floatx4){0.f,0.f,0.f,0.f};
    for (int k0 = k0s; k0 < k0s + KSEG; k0 += 32){
        int c0 = (k0 >> 1) + kg*4;
        shortx8 af[2];
        #pragma unroll
        for (int mi = 0; mi < 2; ++mi){
            int b = wv2*32 + mi*16 + mr;
            #pragma unroll
            for (int cc = 0; cc < 4; ++cc){
                af[mi][2*cc]   = (short)Ain[(2*d)*32768   + b*256 + c0 + cc];
                af[mi][2*cc+1] = (short)Ain[(2*d+1)*32768 + b*256 + c0 + cc];
            }
        }
        shortx8 bf_[4];
        #pragma unroll
        for (int ni = 0; ni < 4; ++ni){
            int o = ob*64 + ni*16 + mr;
            int base = ((o*256 + c0)*dl + d)*2;
            #pragma unroll
            for (int cc = 0; cc < 4; ++cc){
                if (WBF){
                    unsigned int u = *(const unsigned int*)(wB + base);
                    bf_[ni][2*cc]   = (short)(u & 0xFFFFu);
                    bf_[ni][2*cc+1] = (short)(u >> 16);
                } else {
                    bf_[ni][2*cc]   = (short)f2bf(wF[base]);
                    bf_[ni][2*cc+1] = (short)f2bf(wF[base+1]);
                }
                base += 2*dl;
            }
        }
        #pragma unroll
        for (int mi = 0; mi < 2; ++mi)
            #pragma unroll
            for (int ni = 0; ni < 4; ++ni)
                acc[mi][ni] = __builtin_amdgcn_mfma_f32_16x16x32_bf16(af[mi], bf_[ni], acc[mi][ni], 0,0,0);
    }
    #pragma unroll
    for (int mi = 0; mi < 2; ++mi)
        #pragma unroll
        for (int ni = 0; ni < 4; ++ni)
            #pragma unroll
            for (int r = 0; r < 4; ++r){
                int b = wv2*32 + mi*16 + kg*4 + r;
                int o = ob*64 + ni*16 + mr;
                unsafeAtomicAdd(outS + (d*128 + b)*256 + o, acc[mi][ni][r]);
            }
}
__global__ __launch_bounds__(256) void tail_k(const int* __restrict__ flag,
        const unsigned short* __restrict__ Ain, const void* __restrict__ wv,
        float* __restrict__ outS, int dl, int ksplit){
    if (*flag) tail_impl<true >(Ain, wv, outS, dl, ksplit);
    else       tail_impl<false>(Ain, wv, outS, dl, ksplit);
}

// ---------------------------------------------------------------------------
// Finalize: A_{l+1}[i] = bf16(relu(S_l[i]) / 16)   (identity index map)
__global__ __launch_bounds__(256) void fin_kernel(const float* __restrict__ S,
        unsigned short* __restrict__ A, int n){
    int i = (blockIdx.x*256 + threadIdx.x)*4;
    if (i + 3 < n){
        float4 v = *(const float4*)(S + i);
        unsigned short r0 = f2bf(fmaxf(v.x,0.f)*0.0625f);
        unsigned short r1 = f2bf(fmaxf(v.y,0.f)*0.0625f);
        unsigned short r2 = f2bf(fmaxf(v.z,0.f)*0.0625f);
        unsigned short r3 = f2bf(fmaxf(v.w,0.f)*0.0625f);
        unsigned int lo = (unsigned int)r0 | ((unsigned int)r1 << 16);
        unsigned int hi = (unsigned int)r2 | ((unsigned int)r3 << 16);
        uint2 u; u.x = lo; u.y = hi;
        *(uint2*)(A + i) = u;
    }
}

// ---------------------------------------------------------------------------
// Epilogue (R1, verified): out[b,o] = (sum_h relu(S9[b,h])/16 * beta[h,o]) / 256
template<bool BF>
__device__ __forceinline__ void epi_impl(const float* __restrict__ S9, const void* __restrict__ beta,
                                         void* __restrict__ out){
    int b = blockIdx.x;
    int lane = threadIdx.x;
    float accv[10];
    #pragma unroll
    for (int o = 0; o < 10; ++o) accv[o] = 0.f;
    for (int h = lane; h < 256; h += 64){
        float y = fmaxf(S9[b*256 + h], 0.f) * 0.0625f;
        #pragma unroll
        for (int o = 0; o < 10; ++o){
            float be = BF ? bf2f(((const unsigned short*)beta)[h*10 + o])
                          : ((const float*)beta)[h*10 + o];
            accv[o] += y * be;
        }
    }
    #pragma unroll
    for (int off = 32; off > 0; off >>= 1){
        #pragma unroll
        for (int o = 0; o < 10; ++o)
            accv[o] += __shfl_down(accv[o], off, 64);
    }
    if (lane == 0){
        #pragma unroll
        for (int o = 0; o < 10; ++o){
            float v = accv[o] * (1.f/256.f);
            if (BF) ((unsigned short*)out)[b*10 + o] = f2bf(v);
            else    ((float*)out)[b*10 + o] = v;
        }
    }
}
__global__ void epi_kernel(const int* __restrict__ flag, const float* __restrict__ S9,
                           const void* __restrict__ beta, void* __restrict__ out){
    if (*flag) epi_impl<true>(S9, beta, out);
    else       epi_impl<false>(S9, beta, out);
}

// ---------------------------------------------------------------------------
extern "C" void kernel_launch(void* const* d_in, const int* in_sizes, int n_in,
                              void* d_out, int out_size, void* d_ws, size_t ws_size,
                              hipStream_t stream) {
    (void)in_sizes; (void)n_in; (void)out_size; (void)ws_size;
    char* wsb = (char*)d_ws;
    int* flag = (int*)wsb;
    // region1: A1, later overwritten by S2..S9 (fp32)
    unsigned short* A1 = (unsigned short*)(wsb + 512);
    float* S2 = (float*)(wsb + 512);
    float* S3 = S2 + 4194304;
    float* S4 = S3 + 2097152;
    float* S5 = S4 + 1048576;
    float* S6 = S5 + 524288;
    float* S7 = S6 + 262144;
    float* S8 = S7 + 131072;
    float* S9 = S8 + 65536;
    // region2: A2, later overlaid by A3..A9
    unsigned short* A2 = (unsigned short*)(wsb + 512 + 33554432);
    unsigned short* A3 = A2;
    unsigned short* A4 = A3 + 4194304;
    unsigned short* A5 = A4 + 2097152;
    unsigned short* A6 = A5 + 1048576;
    unsigned short* A7 = A6 + 524288;
    unsigned short* A8 = A7 + 262144;
    unsigned short* A9 = A8 + 131072;

    probe_kernel<<<1, 256, 0, stream>>>((const unsigned int*)d_in[0], flag);
    l0_kernel<<<512, 256, 0, stream>>>(flag, d_in[0], d_in[1], A1);
    // l1: reads A1 (region1), writes bf16 A2 (region2) -- ks=1, non-atomic
    layer_main_k<false><<<256, 256, 0, stream>>>(flag, A1, d_in[2], A2, 256, 1);
    // A1 now dead: zero S region (covers S2..S9) for atomic layers
    hipMemsetAsync(S2, 0, 33423360, stream);
    layer_main_k<true ><<<256, 256, 0, stream>>>(flag, A2, d_in[3], S2, 128, 2);
    fin_kernel<<<4096, 256, 0, stream>>>(S2, A3, 4194304);
    layer_main_k<true ><<<256, 256, 0, stream>>>(flag, A3, d_in[4], S3, 64, 4);
    fin_kernel<<<2048, 256, 0, stream>>>(S3, A4, 2097152);
    layer_main_k<true ><<<256, 256, 0, stream>>>(flag, A4, d_in[5], S4, 32, 8);
    fin_kernel<<<1024, 256, 0, stream>>>(S4, A5, 1048576);
    layer_main_k<true ><<<256, 256, 0, stream>>>(flag, A5, d_in[6], S5, 16, 16);
    fin_kernel<<<512, 256, 0, stream>>>(S5, A6, 524288);
    layer_main_k<true ><<<128, 256, 0, stream>>>(flag, A6, d_in[7], S6, 8, 16);
    fin_kernel<<<256, 256, 0, stream>>>(S6, A7, 262144);
    layer_main_k<true ><<<64, 256, 0, stream>>>(flag, A7, d_in[8], S7, 4, 16);
    fin_kernel<<<128, 256, 0, stream>>>(S7, A8, 131072);
    tail_k<<<128, 256, 0, stream>>>(flag, A8, d_in[9], S8, 2, 16);
    fin_kernel<<<64, 256, 0, stream>>>(S8, A9, 65536);
    tail_k<<<64, 256, 0, stream>>>(flag, A9, d_in[10], S9, 1, 16);
    epi_kernel<<<128, 64, 0, stream>>>(flag, S9, d_in[11], d_out);
}